// Round 24
// baseline (111.804 us; speedup 1.0000x reference)
//
#include <hip/hip_runtime.h>
#include <hip/hip_bf16.h>
#include <stdint.h>

// Problem constants: B=4, S=1024, D=1024, H=16, DEPTH=64
#define B_ 4
#define S_ 1024
#define D_ 1024
#define H_ 16
#define DEPTH_ 64

typedef __attribute__((ext_vector_type(8))) short bf16x8;   // 8 bf16 (4 VGPRs)
typedef __attribute__((ext_vector_type(4))) float f32x4;    // MFMA C/D + vec loads
typedef unsigned short ubf16;

#define BAR() do { asm volatile("" ::: "memory"); __builtin_amdgcn_s_barrier(); asm volatile("" ::: "memory"); } while (0)

__device__ __forceinline__ ubf16 f2bf(float f) {
  union { float f; unsigned u; } v; v.f = f;
  unsigned r = v.u + 0x7fffu + ((v.u >> 16) & 1u);  // RNE
  return (ubf16)(r >> 16);
}

__device__ __forceinline__ void async16(void* lds, const void* g) {
  __builtin_amdgcn_global_load_lds(
      (const __attribute__((address_space(1))) void*)g,
      (__attribute__((address_space(3))) void*)lds, 16, 0, 0);
}

// ---------------- W [K,N] fp32 -> W^T [N,K] bf16 (4 weights) ----------------
struct Tp4 { const float* W[4]; ubf16* WT[4]; };
__global__ __launch_bounds__(256) void transpose4_bf16(Tp4 a) {
  __shared__ float tile[32][33];
  const float* W = a.W[blockIdx.z];
  ubf16* WT = a.WT[blockIdx.z];
  int n0 = blockIdx.x * 32, k0 = blockIdx.y * 32;
  int tx = threadIdx.x & 31, ty = threadIdx.x >> 5;  // 32 x 8
#pragma unroll
  for (int i = 0; i < 4; ++i)
    tile[ty + i * 8][tx] = W[(size_t)(k0 + ty + i * 8) * D_ + n0 + tx];
  __syncthreads();
#pragma unroll
  for (int i = 0; i < 4; ++i)
    WT[(size_t)(n0 + ty + i * 8) * D_ + k0 + tx] = f2bf(tile[tx][ty + i * 8]);
}

// ---------------- QKV GEMM with FUSED fp32->bf16 on the A path (R21 best:
// 256 thr = 4 waves; 2 A reg-loads + 2 B gload_lds per thread per iter;
// counted vmcnt(4) retires B(t) while A(t+1)+B(t+1) stay in flight) ----------
struct GemmUnitF {
  const float* A; const ubf16* BT; const float* bias; void* out; int mode;
};
struct GemmArgsF { GemmUnitF u[3]; };

__global__ __launch_bounds__(256) void gemm_qkv_fused(GemmArgsF args) {
  const GemmUnitF gu = args.u[blockIdx.z];
  const int orig = blockIdx.x + (blockIdx.y << 3);
  const int xcd = orig & 7, j = orig >> 3;
  const int bm0 = (xcd * 4 + (j & 3)) * 128;
  const int bn0 = (j >> 2) * 128;
  const int tid = threadIdx.x, wid = tid >> 6, lane = tid & 63;
  const int wr = wid >> 1, wc = wid & 1;           // 2x2 waves, each 64x64
  const int l15 = lane & 15, l4 = lane >> 4;
  const int K = 1024;

  __shared__ __align__(16) ubf16 As[2][128 * 32];  // 8KB per buf
  __shared__ __align__(16) ubf16 Bs[2][128 * 32];
  f32x4 acc[4][4] = {};

  int cc0, cc1;
  const float* aP0; const float* aP1;
  const ubf16* bP0; const ubf16* bP1;
  {
    cc0 = tid;           int r0 = cc0 >> 2, s0 = cc0 & 3, g0 = s0 ^ ((r0 >> 1) & 3);
    cc1 = 256 + tid;     int r1 = cc1 >> 2, s1 = cc1 & 3, g1 = s1 ^ ((r1 >> 1) & 3);
    aP0 = gu.A + (size_t)(bm0 + r0) * K + g0 * 8;
    aP1 = gu.A + (size_t)(bm0 + r1) * K + g1 * 8;
    bP0 = gu.BT + (size_t)(bn0 + r0) * K + g0 * 8;
    bP1 = gu.BT + (size_t)(bn0 + r1) * K + g1 * 8;
  }
  int aOff[4], bOff[4];
#pragma unroll
  for (int f = 0; f < 4; ++f) {
    int ra = wr * 64 + f * 16 + l15;
    aOff[f] = ra * 64 + (l4 ^ ((ra >> 1) & 3)) * 16;
    int rb = wc * 64 + f * 16 + l15;
    bOff[f] = rb * 64 + (l4 ^ ((rb >> 1) & 3)) * 16;
  }

  // prologue: tile 0 — A loads first, then B stages; convert+write A0.
  {
    f32x4 a00 = *(const f32x4*)aP0, a01 = *(const f32x4*)(aP0 + 4); aP0 += 32;
    f32x4 a10 = *(const f32x4*)aP1, a11 = *(const f32x4*)(aP1 + 4); aP1 += 32;
    async16((char*)&Bs[0][0] + wid * 1024, bP0); bP0 += 32;
    async16((char*)&Bs[0][0] + 4096 + wid * 1024, bP1); bP1 += 32;
    bf16x8 w0, w1;
#pragma unroll
    for (int q = 0; q < 4; ++q) {
      w0[q] = (short)f2bf(a00[q]); w0[4 + q] = (short)f2bf(a01[q]);
      w1[q] = (short)f2bf(a10[q]); w1[4 + q] = (short)f2bf(a11[q]);
    }
    *(bf16x8*)((char*)&As[0][0] + cc0 * 16) = w0;
    *(bf16x8*)((char*)&As[0][0] + cc1 * 16) = w1;
    asm volatile("s_waitcnt lgkmcnt(0)" ::: "memory");
  }

#pragma unroll 1
  for (int t = 0; t < 31; ++t) {
    const int cur = t & 1;
    // region 1: issue A(t+1) reg-loads, then B(t+1) -> LDS
    f32x4 a00 = *(const f32x4*)aP0, a01 = *(const f32x4*)(aP0 + 4); aP0 += 32;
    f32x4 a10 = *(const f32x4*)aP1, a11 = *(const f32x4*)(aP1 + 4); aP1 += 32;
    async16((char*)&Bs[cur ^ 1][0] + wid * 1024, bP0); bP0 += 32;
    async16((char*)&Bs[cur ^ 1][0] + 4096 + wid * 1024, bP1); bP1 += 32;
    __builtin_amdgcn_sched_barrier(0);
    // region 2: B(t) resident (oldest 2 of 6) + sync; MFMA on tile t
    asm volatile("s_waitcnt vmcnt(4)" ::: "memory");
    __builtin_amdgcn_s_barrier();
    __builtin_amdgcn_sched_barrier(0);
    bf16x8 af[4], bfr[4];
#pragma unroll
    for (int mi = 0; mi < 4; ++mi)
      af[mi] = *(const bf16x8*)((const char*)&As[cur][0] + aOff[mi]);
#pragma unroll
    for (int ni = 0; ni < 4; ++ni)
      bfr[ni] = *(const bf16x8*)((const char*)&Bs[cur][0] + bOff[ni]);
#pragma unroll
    for (int mi = 0; mi < 4; ++mi)
#pragma unroll
      for (int ni = 0; ni < 4; ++ni)
        acc[mi][ni] = __builtin_amdgcn_mfma_f32_16x16x32_bf16(af[mi], bfr[ni], acc[mi][ni], 0, 0, 0);
    __builtin_amdgcn_sched_barrier(0);
    // region 3: convert+write A(t+1); make visible; end-of-window sync
    bf16x8 w0, w1;
#pragma unroll
    for (int q = 0; q < 4; ++q) {
      w0[q] = (short)f2bf(a00[q]); w0[4 + q] = (short)f2bf(a01[q]);
      w1[q] = (short)f2bf(a10[q]); w1[4 + q] = (short)f2bf(a11[q]);
    }
    *(bf16x8*)((char*)&As[cur ^ 1][0] + cc0 * 16) = w0;
    *(bf16x8*)((char*)&As[cur ^ 1][0] + cc1 * 16) = w1;
    asm volatile("s_waitcnt lgkmcnt(0)" ::: "memory");
    __builtin_amdgcn_s_barrier();
  }
  asm volatile("s_waitcnt vmcnt(0)" ::: "memory");
  __builtin_amdgcn_s_barrier();
  {
    bf16x8 af[4], bfr[4];
#pragma unroll
    for (int mi = 0; mi < 4; ++mi)
      af[mi] = *(const bf16x8*)((const char*)&As[1][0] + aOff[mi]);
#pragma unroll
    for (int ni = 0; ni < 4; ++ni)
      bfr[ni] = *(const bf16x8*)((const char*)&Bs[1][0] + bOff[ni]);
#pragma unroll
    for (int mi = 0; mi < 4; ++mi)
#pragma unroll
      for (int ni = 0; ni < 4; ++ni)
        acc[mi][ni] = __builtin_amdgcn_mfma_f32_16x16x32_bf16(af[mi], bfr[ni], acc[mi][ni], 0, 0, 0);
  }

  float bv[4];
#pragma unroll
  for (int ni = 0; ni < 4; ++ni) bv[ni] = gu.bias[bn0 + wc * 64 + ni * 16 + l15];
#pragma unroll
  for (int mi = 0; mi < 4; ++mi) {
#pragma unroll
    for (int ni = 0; ni < 4; ++ni) {
#pragma unroll
      for (int r = 0; r < 4; ++r) {
        int m = bm0 + wr * 64 + mi * 16 + l4 * 4 + r;   // C/D: row=(lane>>4)*4+reg
        int n = bn0 + wc * 64 + ni * 16 + l15;          //      col=lane&15
        float v = acc[mi][ni][r] + bv[ni];
        if (gu.mode == 0) {
          ((ubf16*)gu.out)[(size_t)m * 1024 + n] = f2bf(v);
        } else {  // mode 1: V^T [B,H,64,S]
          int b = m >> 10, s = m & 1023, h = n >> 6, d = n & 63;
          ((ubf16*)gu.out)[(((size_t)(b * H_ + h)) * DEPTH_ + d) * S_ + s] = f2bf(v);
        }
      }
    }
  }
}

// ---------------- bf16-A GEMM, 512 thr = 8 waves on the same 128x128 tile
// (R23 best for out-projection; same bytes, waves/CU 4->8; vmcnt(2)) ---------
struct GemmUnit {
  const ubf16* A; const ubf16* BT; const float* bias; void* out; int mode;
};
struct GemmArgs { GemmUnit u[3]; };

__global__ __launch_bounds__(512) void gemm_bt(GemmArgs args, int M, int N) {
  const GemmUnit gu = args.u[blockIdx.z];
  const int orig = blockIdx.x + (blockIdx.y << 3);
  const int xcd = orig & 7, j = orig >> 3;
  const int bm0 = (xcd * 4 + (j & 3)) * 128;
  const int bn0 = (j >> 2) * 128;
  const int tid = threadIdx.x, wid = tid >> 6, lane = tid & 63;
  const int wm = wid >> 2, wn = wid & 3;           // 2x4 waves, each 64x32
  const int l15 = lane & 15, l4 = lane >> 4;
  const int K = 1024;

  __shared__ __align__(16) ubf16 As[2][128 * 32];
  __shared__ __align__(16) ubf16 Bs[2][128 * 32];
  f32x4 acc[4][2] = {};

  const ubf16* aCur; const ubf16* bCur;
  {
    int r = tid >> 2, s = tid & 3;
    int cg = s ^ ((r >> 1) & 3);
    aCur = gu.A + (size_t)(bm0 + r) * K + cg * 8;
    bCur = gu.BT + (size_t)(bn0 + r) * K + cg * 8;
  }
  auto stageAdv = [&](int bf) {   // 2 gload_lds per thread per tile
    async16((char*)&As[bf][0] + wid * 1024, aCur); aCur += 32;
    async16((char*)&Bs[bf][0] + wid * 1024, bCur); bCur += 32;
  };
  int aOff[4], bOff[2];
#pragma unroll
  for (int f = 0; f < 4; ++f) {
    int ra = wm * 64 + f * 16 + l15;
    aOff[f] = ra * 64 + (l4 ^ ((ra >> 1) & 3)) * 16;
  }
#pragma unroll
  for (int f = 0; f < 2; ++f) {
    int rb = wn * 32 + f * 16 + l15;
    bOff[f] = rb * 64 + (l4 ^ ((rb >> 1) & 3)) * 16;
  }

  stageAdv(0);
  for (int t = 0; t < 32; ++t) {
    const int cur = t & 1;
    if (t < 31) {
      stageAdv(cur ^ 1);
      asm volatile("s_waitcnt vmcnt(2)" ::: "memory");  // tile t resident; t+1 in flight
    } else {
      asm volatile("s_waitcnt vmcnt(0)" ::: "memory");
    }
    BAR();
    bf16x8 af[4], bfr[2];
#pragma unroll
    for (int mi = 0; mi < 4; ++mi)
      af[mi] = *(const bf16x8*)((const char*)&As[cur][0] + aOff[mi]);
#pragma unroll
    for (int ni = 0; ni < 2; ++ni)
      bfr[ni] = *(const bf16x8*)((const char*)&Bs[cur][0] + bOff[ni]);
#pragma unroll
    for (int mi = 0; mi < 4; ++mi)
#pragma unroll
      for (int ni = 0; ni < 2; ++ni)
        acc[mi][ni] = __builtin_amdgcn_mfma_f32_16x16x32_bf16(af[mi], bfr[ni], acc[mi][ni], 0, 0, 0);
    BAR();
  }

  float bv[2];
#pragma unroll
  for (int ni = 0; ni < 2; ++ni) bv[ni] = gu.bias[bn0 + wn * 32 + ni * 16 + l15];
#pragma unroll
  for (int mi = 0; mi < 4; ++mi) {
#pragma unroll
    for (int ni = 0; ni < 2; ++ni) {
#pragma unroll
      for (int r = 0; r < 4; ++r) {
        int m = bm0 + wm * 64 + mi * 16 + l4 * 4 + r;
        int n = bn0 + wn * 32 + ni * 16 + l15;
        float v = acc[mi][ni][r] + bv[ni];
        if (gu.mode == 0) {
          ((ubf16*)gu.out)[(size_t)m * N + n] = f2bf(v);
        } else if (gu.mode == 1) {
          int b = m >> 10, s = m & 1023, h = n >> 6, d = n & 63;
          ((ubf16*)gu.out)[(((size_t)(b * H_ + h)) * DEPTH_ + d) * S_ + s] = f2bf(v);
        } else {
          ((float*)gu.out)[(size_t)m * N + n] = v;
        }
      }
    }
  }
}

// ---------------- flash attention: 512-thread blocks = 8 waves x 32 q-rows
// (R19 best: K/V staged once per 256 q-rows) ----------------
__global__ __launch_bounds__(512) void attention_fwd(
    const ubf16* __restrict__ Q, const ubf16* __restrict__ Kg,
    const ubf16* __restrict__ VT, const float* __restrict__ mask,
    ubf16* __restrict__ ctx) {
  const int lid = blockIdx.y * 4 + blockIdx.x;
  const int t0 = (lid & 7) * 32 + (lid >> 3);
  const int qt = t0 & 3, bh = t0 >> 2;
  const int b = bh >> 4, h = bh & 15;
  const int tid = threadIdx.x, wid = tid >> 6, lane = tid & 63;
  const int l15 = lane & 15, l4 = lane >> 4;
  const int q0 = qt * 256 + wid * 32;

  __shared__ __align__(16) ubf16 Ks[2][4096];
  __shared__ __align__(16) ubf16 Vs[2][4096];
  __shared__ __align__(16) ubf16 Ps[8][32][72];

  const ubf16* kb = Kg + ((size_t)(b * S_)) * D_ + h * DEPTH_;
  const ubf16* vb = VT + ((size_t)bh) * DEPTH_ * S_;

  bf16x8 aq[2][2];
#pragma unroll
  for (int mi = 0; mi < 2; ++mi)
#pragma unroll
    for (int kk = 0; kk < 2; ++kk)
      aq[mi][kk] = *(const bf16x8*)&Q[((size_t)(b * S_ + q0 + mi * 16 + l15)) * D_ +
                                      h * DEPTH_ + kk * 32 + l4 * 8];

  bf16x8 ones;
#pragma unroll
  for (int j = 0; j < 8; ++j) ones[j] = (short)0x3F80;

  f32x4 cacc[2][4] = {};
  f32x4 csum[2] = {};

  const float* mrow = mask + b * S_;
  const float C1 = 0.125f * 1.44269504f;
  const float CM = -1.0e9f * 1.44269504f;

  auto stage = [&](int bf, int kt) {
    int r = tid >> 3, cg = (tid & 7) ^ (r & 7);
    async16((char*)&Ks[bf][0] + wid * 1024, kb + (size_t)(kt + r) * D_ + cg * 8);
    async16((char*)&Vs[bf][0] + wid * 1024, vb + (size_t)r * S_ + kt + cg * 8);
  };

  stage(0, 0);
  __syncthreads();

  for (int t = 0; t < 16; ++t) {
    const int cur = t & 1;
    const int kt = t * 64;
    if (t < 15) stage(cur ^ 1, kt + 64);

    bf16x8 kf[4][2];
#pragma unroll
    for (int nf = 0; nf < 4; ++nf)
#pragma unroll
      for (int kk = 0; kk < 2; ++kk) {
        int kr = nf * 16 + l15;
        int c16 = (kk * 4 + l4) ^ (kr & 7);
        kf[nf][kk] = *(const bf16x8*)((const char*)&Ks[cur][0] + kr * 128 + c16 * 16);
      }
    bf16x8 vf[4][2];
#pragma unroll
    for (int df = 0; df < 4; ++df)
#pragma unroll
      for (int kk = 0; kk < 2; ++kk) {
        int dr = df * 16 + l15;
        int c16 = (kk * 4 + l4) ^ (dr & 7);
        vf[df][kk] = *(const bf16x8*)((const char*)&Vs[cur][0] + dr * 128 + c16 * 16);
      }

    f32x4 sc[2][4];
#pragma unroll
    for (int mi = 0; mi < 2; ++mi)
#pragma unroll
      for (int nf = 0; nf < 4; ++nf) {
        f32x4 z = {0.f, 0.f, 0.f, 0.f};
        z = __builtin_amdgcn_mfma_f32_16x16x32_bf16(aq[mi][0], kf[nf][0], z, 0, 0, 0);
        z = __builtin_amdgcn_mfma_f32_16x16x32_bf16(aq[mi][1], kf[nf][1], z, 0, 0, 0);
        sc[mi][nf] = z;
      }

    float mvl[4];
#pragma unroll
    for (int nf = 0; nf < 4; ++nf) mvl[nf] = mrow[kt + nf * 16 + l15] * CM;

#pragma unroll
    for (int mi = 0; mi < 2; ++mi)
#pragma unroll
      for (int nf = 0; nf < 4; ++nf)
#pragma unroll
        for (int r = 0; r < 4; ++r) {
          float p = __builtin_amdgcn_exp2f(fmaf(sc[mi][nf][r], C1, mvl[nf]));
          Ps[wid][mi * 16 + l4 * 4 + r][nf * 16 + l15] = f2bf(p);
        }

    bf16x8 pf[2][2];
#pragma unroll
    for (int mi = 0; mi < 2; ++mi)
#pragma unroll
      for (int kk = 0; kk < 2; ++kk)
        pf[mi][kk] = *(const bf16x8*)&Ps[wid][mi * 16 + l15][kk * 32 + l4 * 8];

#pragma unroll
    for (int mi = 0; mi < 2; ++mi) {
#pragma unroll
      for (int df = 0; df < 4; ++df) {
        cacc[mi][df] = __builtin_amdgcn_mfma_f32_16x16x32_bf16(pf[mi][0], vf[df][0], cacc[mi][df], 0, 0, 0);
        cacc[mi][df] = __builtin_amdgcn_mfma_f32_16x16x32_bf16(pf[mi][1], vf[df][1], cacc[mi][df], 0, 0, 0);
      }
      csum[mi] = __builtin_amdgcn_mfma_f32_16x16x32_bf16(pf[mi][0], ones, csum[mi], 0, 0, 0);
      csum[mi] = __builtin_amdgcn_mfma_f32_16x16x32_bf16(pf[mi][1], ones, csum[mi], 0, 0, 0);
    }

    __syncthreads();
  }

#pragma unroll
  for (int mi = 0; mi < 2; ++mi) {
    float inv[4];
#pragma unroll
    for (int r = 0; r < 4; ++r) inv[r] = 1.0f / csum[mi][r];
#pragma unroll
    for (int df = 0; df < 4; ++df)
#pragma unroll
      for (int r = 0; r < 4; ++r) {
        int srow = q0 + mi * 16 + l4 * 4 + r;
        float v = cacc[mi][df][r] * inv[r];
        ctx[((size_t)(b * S_ + srow)) * D_ + h * DEPTH_ + df * 16 + l15] = f2bf(v);
      }
  }
}

extern "C" void kernel_launch(void* const* d_in, const int* in_sizes, int n_in,
                              void* d_out, int out_size, void* d_ws, size_t ws_size,
                              hipStream_t stream) {
  const float* query  = (const float*)d_in[0];
  const float* key_in = (const float*)d_in[1];
  const float* value  = (const float*)d_in[2];
  const float* mask   = (const float*)d_in[3];
  const float* wq = (const float*)d_in[4];
  const float* bq = (const float*)d_in[5];
  const float* wk = (const float*)d_in[6];
  const float* bk = (const float*)d_in[7];
  const float* wv = (const float*)d_in[8];
  const float* bv = (const float*)d_in[9];
  const float* wo = (const float*)d_in[10];
  const float* bo = (const float*)d_in[11];

  char* ws = (char*)d_ws;
  const size_t MB = 1024 * 1024;
  ubf16* WqT = (ubf16*)(ws + 24 * MB);
  ubf16* WkT = (ubf16*)(ws + 26 * MB);
  ubf16* WvT = (ubf16*)(ws + 28 * MB);
  ubf16* WoT = (ubf16*)(ws + 30 * MB);
  ubf16* Qb  = (ubf16*)(ws + 32 * MB);
  ubf16* Kb  = (ubf16*)(ws + 40 * MB);
  ubf16* VTb = (ubf16*)(ws + 48 * MB);
  ubf16* Ctx = (ubf16*)(ws + 56 * MB);

  Tp4 t4;
  t4.W[0] = wq; t4.WT[0] = WqT;
  t4.W[1] = wk; t4.WT[1] = WkT;
  t4.W[2] = wv; t4.WT[2] = WvT;
  t4.W[3] = wo; t4.WT[3] = WoT;
  transpose4_bf16<<<dim3(32, 32, 4), dim3(256), 0, stream>>>(t4);

  GemmArgsF g1;
  g1.u[0] = {query,  WqT, bq, (void*)Qb, 0};
  g1.u[1] = {key_in, WkT, bk, (void*)Kb, 0};
  g1.u[2] = {value,  WvT, bv, (void*)VTb, 1};
  gemm_qkv_fused<<<dim3(8, 32, 3), dim3(256), 0, stream>>>(g1);

  attention_fwd<<<dim3(4, 64), dim3(512), 0, stream>>>(Qb, Kb, VTb, mask, Ctx);

  GemmArgs g2;
  g2.u[0] = {Ctx, WoT, bo, d_out, 2};
  g2.u[1] = g2.u[0];
  g2.u[2] = g2.u[0];
  gemm_bt<<<dim3(8, 32, 1), dim3(512), 0, stream>>>(g2, 4096, 1024);
}

// Round 25
// 109.713 us; speedup vs baseline: 1.0191x; 1.0191x over previous
//
#include <hip/hip_runtime.h>
#include <hip/hip_bf16.h>
#include <stdint.h>

// Problem constants: B=4, S=1024, D=1024, H=16, DEPTH=64
#define B_ 4
#define S_ 1024
#define D_ 1024
#define H_ 16
#define DEPTH_ 64

typedef __attribute__((ext_vector_type(8))) short bf16x8;   // 8 bf16 (4 VGPRs)
typedef __attribute__((ext_vector_type(4))) float f32x4;    // MFMA C/D + vec loads
typedef unsigned short ubf16;

#define BAR() do { asm volatile("" ::: "memory"); __builtin_amdgcn_s_barrier(); asm volatile("" ::: "memory"); } while (0)

__device__ __forceinline__ ubf16 f2bf(float f) {
  union { float f; unsigned u; } v; v.f = f;
  unsigned r = v.u + 0x7fffu + ((v.u >> 16) & 1u);  // RNE
  return (ubf16)(r >> 16);
}

__device__ __forceinline__ void async16(void* lds, const void* g) {
  __builtin_amdgcn_global_load_lds(
      (const __attribute__((address_space(1))) void*)g,
      (__attribute__((address_space(3))) void*)lds, 16, 0, 0);
}

// ---------------- W [K,N] fp32 -> W^T [N,K] bf16 (4 weights) ----------------
struct Tp4 { const float* W[4]; ubf16* WT[4]; };
__global__ __launch_bounds__(256) void transpose4_bf16(Tp4 a) {
  __shared__ float tile[32][33];
  const float* W = a.W[blockIdx.z];
  ubf16* WT = a.WT[blockIdx.z];
  int n0 = blockIdx.x * 32, k0 = blockIdx.y * 32;
  int tx = threadIdx.x & 31, ty = threadIdx.x >> 5;  // 32 x 8
#pragma unroll
  for (int i = 0; i < 4; ++i)
    tile[ty + i * 8][tx] = W[(size_t)(k0 + ty + i * 8) * D_ + n0 + tx];
  __syncthreads();
#pragma unroll
  for (int i = 0; i < 4; ++i)
    WT[(size_t)(n0 + ty + i * 8) * D_ + k0 + tx] = f2bf(tile[tx][ty + i * 8]);
}

// ---------------- QKV GEMM: fused fp32->bf16 A-path, 512 thr = 8 waves on the
// SAME 128x128 tile (waves-per-byte lever: same grid 768, same staged bytes,
// waves/CU 12->24). Each wave owns 64x32 out (2m x 4n); each thread stages
// 2 A reg-loads + 1 B gload_lds per iter -> counted vmcnt(3) retires B(t)
// while A(t+1)+B(t+1) stay in flight (region3's a00/a01 use forces vmcnt<=1).
struct GemmUnitF {
  const float* A; const ubf16* BT; const float* bias; void* out; int mode;
};
struct GemmArgsF { GemmUnitF u[3]; };

__global__ __launch_bounds__(512) void gemm_qkv_fused(GemmArgsF args) {
  const GemmUnitF gu = args.u[blockIdx.z];
  const int orig = blockIdx.x + (blockIdx.y << 3);
  const int xcd = orig & 7, j = orig >> 3;
  const int bm0 = (xcd * 4 + (j & 3)) * 128;
  const int bn0 = (j >> 2) * 128;
  const int tid = threadIdx.x, wid = tid >> 6, lane = tid & 63;
  const int wm = wid >> 2, wn = wid & 3;           // 2x4 waves, each 64x32
  const int l15 = lane & 15, l4 = lane >> 4;
  const int K = 1024;

  __shared__ __align__(16) ubf16 As[2][128 * 32];  // 8KB per buf
  __shared__ __align__(16) ubf16 Bs[2][128 * 32];
  f32x4 acc[4][2] = {};

  // per-thread staging: chunk cc = tid (512 chunks per 8KB tile);
  // row r=tid>>2, slot s=tid&3, pre-swizzled source chunk cg=s^((r>>1)&3).
  const float* aP0; const ubf16* bP0;
  {
    int r0 = tid >> 2, s0 = tid & 3, g0 = s0 ^ ((r0 >> 1) & 3);
    aP0 = gu.A + (size_t)(bm0 + r0) * K + g0 * 8;
    bP0 = gu.BT + (size_t)(bn0 + r0) * K + g0 * 8;
  }
  int aOff[4], bOff[2];
#pragma unroll
  for (int f = 0; f < 4; ++f) {
    int ra = wm * 64 + f * 16 + l15;
    aOff[f] = ra * 64 + (l4 ^ ((ra >> 1) & 3)) * 16;
  }
#pragma unroll
  for (int f = 0; f < 2; ++f) {
    int rb = wn * 32 + f * 16 + l15;
    bOff[f] = rb * 64 + (l4 ^ ((rb >> 1) & 3)) * 16;
  }

  // prologue: tile 0 — A loads first, then B stages; convert+write A0.
  {
    f32x4 a00 = *(const f32x4*)aP0, a01 = *(const f32x4*)(aP0 + 4); aP0 += 32;
    async16((char*)&Bs[0][0] + wid * 1024, bP0); bP0 += 32;
    bf16x8 w0;
#pragma unroll
    for (int q = 0; q < 4; ++q) {
      w0[q] = (short)f2bf(a00[q]); w0[4 + q] = (short)f2bf(a01[q]);
    }
    *(bf16x8*)((char*)&As[0][0] + tid * 16) = w0;
    asm volatile("s_waitcnt lgkmcnt(0)" ::: "memory");
    BAR();
  }

#pragma unroll 1
  for (int t = 0; t < 31; ++t) {
    const int cur = t & 1;
    // region 1: issue A(t+1) reg-loads, then B(t+1) -> LDS
    f32x4 a00 = *(const f32x4*)aP0, a01 = *(const f32x4*)(aP0 + 4); aP0 += 32;
    async16((char*)&Bs[cur ^ 1][0] + wid * 1024, bP0); bP0 += 32;
    __builtin_amdgcn_sched_barrier(0);
    // region 2: B(t) resident (oldest of 4) + sync; MFMA on tile t
    asm volatile("s_waitcnt vmcnt(3)" ::: "memory");
    __builtin_amdgcn_s_barrier();
    __builtin_amdgcn_sched_barrier(0);
    bf16x8 af[4], bfr[2];
#pragma unroll
    for (int mi = 0; mi < 4; ++mi)
      af[mi] = *(const bf16x8*)((const char*)&As[cur][0] + aOff[mi]);
#pragma unroll
    for (int ni = 0; ni < 2; ++ni)
      bfr[ni] = *(const bf16x8*)((const char*)&Bs[cur][0] + bOff[ni]);
#pragma unroll
    for (int mi = 0; mi < 4; ++mi)
#pragma unroll
      for (int ni = 0; ni < 2; ++ni)
        acc[mi][ni] = __builtin_amdgcn_mfma_f32_16x16x32_bf16(af[mi], bfr[ni], acc[mi][ni], 0, 0, 0);
    __builtin_amdgcn_sched_barrier(0);
    // region 3: convert+write A(t+1); make visible; end-of-window sync
    bf16x8 w0;
#pragma unroll
    for (int q = 0; q < 4; ++q) {
      w0[q] = (short)f2bf(a00[q]); w0[4 + q] = (short)f2bf(a01[q]);
    }
    *(bf16x8*)((char*)&As[cur ^ 1][0] + tid * 16) = w0;
    asm volatile("s_waitcnt lgkmcnt(0)" ::: "memory");
    __builtin_amdgcn_s_barrier();
  }
  asm volatile("s_waitcnt vmcnt(0)" ::: "memory");
  __builtin_amdgcn_s_barrier();
  {
    bf16x8 af[4], bfr[2];
#pragma unroll
    for (int mi = 0; mi < 4; ++mi)
      af[mi] = *(const bf16x8*)((const char*)&As[1][0] + aOff[mi]);
#pragma unroll
    for (int ni = 0; ni < 2; ++ni)
      bfr[ni] = *(const bf16x8*)((const char*)&Bs[1][0] + bOff[ni]);
#pragma unroll
    for (int mi = 0; mi < 4; ++mi)
#pragma unroll
      for (int ni = 0; ni < 2; ++ni)
        acc[mi][ni] = __builtin_amdgcn_mfma_f32_16x16x32_bf16(af[mi], bfr[ni], acc[mi][ni], 0, 0, 0);
  }

  float bv[2];
#pragma unroll
  for (int ni = 0; ni < 2; ++ni) bv[ni] = gu.bias[bn0 + wn * 32 + ni * 16 + l15];
#pragma unroll
  for (int mi = 0; mi < 4; ++mi) {
#pragma unroll
    for (int ni = 0; ni < 2; ++ni) {
#pragma unroll
      for (int r = 0; r < 4; ++r) {
        int m = bm0 + wm * 64 + mi * 16 + l4 * 4 + r;   // C/D: row=(lane>>4)*4+reg
        int n = bn0 + wn * 32 + ni * 16 + l15;          //      col=lane&15
        float v = acc[mi][ni][r] + bv[ni];
        if (gu.mode == 0) {
          ((ubf16*)gu.out)[(size_t)m * 1024 + n] = f2bf(v);
        } else {  // mode 1: V^T [B,H,64,S]
          int b = m >> 10, s = m & 1023, h = n >> 6, d = n & 63;
          ((ubf16*)gu.out)[(((size_t)(b * H_ + h)) * DEPTH_ + d) * S_ + s] = f2bf(v);
        }
      }
    }
  }
}

// ---------------- bf16-A GEMM, 512 thr = 8 waves on the same 128x128 tile
// (out-projection; same bytes, waves/CU 4->8; vmcnt(2) counted) --------------
struct GemmUnit {
  const ubf16* A; const ubf16* BT; const float* bias; void* out; int mode;
};
struct GemmArgs { GemmUnit u[3]; };

__global__ __launch_bounds__(512) void gemm_bt(GemmArgs args, int M, int N) {
  const GemmUnit gu = args.u[blockIdx.z];
  const int orig = blockIdx.x + (blockIdx.y << 3);
  const int xcd = orig & 7, j = orig >> 3;
  const int bm0 = (xcd * 4 + (j & 3)) * 128;
  const int bn0 = (j >> 2) * 128;
  const int tid = threadIdx.x, wid = tid >> 6, lane = tid & 63;
  const int wm = wid >> 2, wn = wid & 3;           // 2x4 waves, each 64x32
  const int l15 = lane & 15, l4 = lane >> 4;
  const int K = 1024;

  __shared__ __align__(16) ubf16 As[2][128 * 32];
  __shared__ __align__(16) ubf16 Bs[2][128 * 32];
  f32x4 acc[4][2] = {};

  const ubf16* aCur; const ubf16* bCur;
  {
    int r = tid >> 2, s = tid & 3;
    int cg = s ^ ((r >> 1) & 3);
    aCur = gu.A + (size_t)(bm0 + r) * K + cg * 8;
    bCur = gu.BT + (size_t)(bn0 + r) * K + cg * 8;
  }
  auto stageAdv = [&](int bf) {   // 2 gload_lds per thread per tile
    async16((char*)&As[bf][0] + wid * 1024, aCur); aCur += 32;
    async16((char*)&Bs[bf][0] + wid * 1024, bCur); bCur += 32;
  };
  int aOff[4], bOff[2];
#pragma unroll
  for (int f = 0; f < 4; ++f) {
    int ra = wm * 64 + f * 16 + l15;
    aOff[f] = ra * 64 + (l4 ^ ((ra >> 1) & 3)) * 16;
  }
#pragma unroll
  for (int f = 0; f < 2; ++f) {
    int rb = wn * 32 + f * 16 + l15;
    bOff[f] = rb * 64 + (l4 ^ ((rb >> 1) & 3)) * 16;
  }

  stageAdv(0);
  for (int t = 0; t < 32; ++t) {
    const int cur = t & 1;
    if (t < 31) {
      stageAdv(cur ^ 1);
      asm volatile("s_waitcnt vmcnt(2)" ::: "memory");  // tile t resident; t+1 in flight
    } else {
      asm volatile("s_waitcnt vmcnt(0)" ::: "memory");
    }
    BAR();
    bf16x8 af[4], bfr[2];
#pragma unroll
    for (int mi = 0; mi < 4; ++mi)
      af[mi] = *(const bf16x8*)((const char*)&As[cur][0] + aOff[mi]);
#pragma unroll
    for (int ni = 0; ni < 2; ++ni)
      bfr[ni] = *(const bf16x8*)((const char*)&Bs[cur][0] + bOff[ni]);
#pragma unroll
    for (int mi = 0; mi < 4; ++mi)
#pragma unroll
      for (int ni = 0; ni < 2; ++ni)
        acc[mi][ni] = __builtin_amdgcn_mfma_f32_16x16x32_bf16(af[mi], bfr[ni], acc[mi][ni], 0, 0, 0);
    BAR();
  }

  float bv[2];
#pragma unroll
  for (int ni = 0; ni < 2; ++ni) bv[ni] = gu.bias[bn0 + wn * 32 + ni * 16 + l15];
#pragma unroll
  for (int mi = 0; mi < 4; ++mi) {
#pragma unroll
    for (int ni = 0; ni < 2; ++ni) {
#pragma unroll
      for (int r = 0; r < 4; ++r) {
        int m = bm0 + wm * 64 + mi * 16 + l4 * 4 + r;
        int n = bn0 + wn * 32 + ni * 16 + l15;
        float v = acc[mi][ni][r] + bv[ni];
        if (gu.mode == 0) {
          ((ubf16*)gu.out)[(size_t)m * N + n] = f2bf(v);
        } else if (gu.mode == 1) {
          int b = m >> 10, s = m & 1023, h = n >> 6, d = n & 63;
          ((ubf16*)gu.out)[(((size_t)(b * H_ + h)) * DEPTH_ + d) * S_ + s] = f2bf(v);
        } else {
          ((float*)gu.out)[(size_t)m * N + n] = v;
        }
      }
    }
  }
}

// ---------------- flash attention: 512-thread blocks = 8 waves x 32 q-rows
// (R19 best: K/V staged once per 256 q-rows) ----------------
__global__ __launch_bounds__(512) void attention_fwd(
    const ubf16* __restrict__ Q, const ubf16* __restrict__ Kg,
    const ubf16* __restrict__ VT, const float* __restrict__ mask,
    ubf16* __restrict__ ctx) {
  const int lid = blockIdx.y * 4 + blockIdx.x;
  const int t0 = (lid & 7) * 32 + (lid >> 3);
  const int qt = t0 & 3, bh = t0 >> 2;
  const int b = bh >> 4, h = bh & 15;
  const int tid = threadIdx.x, wid = tid >> 6, lane = tid & 63;
  const int l15 = lane & 15, l4 = lane >> 4;
  const int q0 = qt * 256 + wid * 32;

  __shared__ __align__(16) ubf16 Ks[2][4096];
  __shared__ __align__(16) ubf16 Vs[2][4096];
  __shared__ __align__(16) ubf16 Ps[8][32][72];

  const ubf16* kb = Kg + ((size_t)(b * S_)) * D_ + h * DEPTH_;
  const ubf16* vb = VT + ((size_t)bh) * DEPTH_ * S_;

  bf16x8 aq[2][2];
#pragma unroll
  for (int mi = 0; mi < 2; ++mi)
#pragma unroll
    for (int kk = 0; kk < 2; ++kk)
      aq[mi][kk] = *(const bf16x8*)&Q[((size_t)(b * S_ + q0 + mi * 16 + l15)) * D_ +
                                      h * DEPTH_ + kk * 32 + l4 * 8];

  bf16x8 ones;
#pragma unroll
  for (int j = 0; j < 8; ++j) ones[j] = (short)0x3F80;

  f32x4 cacc[2][4] = {};
  f32x4 csum[2] = {};

  const float* mrow = mask + b * S_;
  const float C1 = 0.125f * 1.44269504f;
  const float CM = -1.0e9f * 1.44269504f;

  auto stage = [&](int bf, int kt) {
    int r = tid >> 3, cg = (tid & 7) ^ (r & 7);
    async16((char*)&Ks[bf][0] + wid * 1024, kb + (size_t)(kt + r) * D_ + cg * 8);
    async16((char*)&Vs[bf][0] + wid * 1024, vb + (size_t)r * S_ + kt + cg * 8);
  };

  stage(0, 0);
  __syncthreads();

  for (int t = 0; t < 16; ++t) {
    const int cur = t & 1;
    const int kt = t * 64;
    if (t < 15) stage(cur ^ 1, kt + 64);

    bf16x8 kf[4][2];
#pragma unroll
    for (int nf = 0; nf < 4; ++nf)
#pragma unroll
      for (int kk = 0; kk < 2; ++kk) {
        int kr = nf * 16 + l15;
        int c16 = (kk * 4 + l4) ^ (kr & 7);
        kf[nf][kk] = *(const bf16x8*)((const char*)&Ks[cur][0] + kr * 128 + c16 * 16);
      }
    bf16x8 vf[4][2];
#pragma unroll
    for (int df = 0; df < 4; ++df)
#pragma unroll
      for (int kk = 0; kk < 2; ++kk) {
        int dr = df * 16 + l15;
        int c16 = (kk * 4 + l4) ^ (dr & 7);
        vf[df][kk] = *(const bf16x8*)((const char*)&Vs[cur][0] + dr * 128 + c16 * 16);
      }

    f32x4 sc[2][4];
#pragma unroll
    for (int mi = 0; mi < 2; ++mi)
#pragma unroll
      for (int nf = 0; nf < 4; ++nf) {
        f32x4 z = {0.f, 0.f, 0.f, 0.f};
        z = __builtin_amdgcn_mfma_f32_16x16x32_bf16(aq[mi][0], kf[nf][0], z, 0, 0, 0);
        z = __builtin_amdgcn_mfma_f32_16x16x32_bf16(aq[mi][1], kf[nf][1], z, 0, 0, 0);
        sc[mi][nf] = z;
      }

    float mvl[4];
#pragma unroll
    for (int nf = 0; nf < 4; ++nf) mvl[nf] = mrow[kt + nf * 16 + l15] * CM;

#pragma unroll
    for (int mi = 0; mi < 2; ++mi)
#pragma unroll
      for (int nf = 0; nf < 4; ++nf)
#pragma unroll
        for (int r = 0; r < 4; ++r) {
          float p = __builtin_amdgcn_exp2f(fmaf(sc[mi][nf][r], C1, mvl[nf]));
          Ps[wid][mi * 16 + l4 * 4 + r][nf * 16 + l15] = f2bf(p);
        }

    bf16x8 pf[2][2];
#pragma unroll
    for (int mi = 0; mi < 2; ++mi)
#pragma unroll
      for (int kk = 0; kk < 2; ++kk)
        pf[mi][kk] = *(const bf16x8*)&Ps[wid][mi * 16 + l15][kk * 32 + l4 * 8];

#pragma unroll
    for (int mi = 0; mi < 2; ++mi) {
#pragma unroll
      for (int df = 0; df < 4; ++df) {
        cacc[mi][df] = __builtin_amdgcn_mfma_f32_16x16x32_bf16(pf[mi][0], vf[df][0], cacc[mi][df], 0, 0, 0);
        cacc[mi][df] = __builtin_amdgcn_mfma_f32_16x16x32_bf16(pf[mi][1], vf[df][1], cacc[mi][df], 0, 0, 0);
      }
      csum[mi] = __builtin_amdgcn_mfma_f32_16x16x32_bf16(pf[mi][0], ones, csum[mi], 0, 0, 0);
      csum[mi] = __builtin_amdgcn_mfma_f32_16x16x32_bf16(pf[mi][1], ones, csum[mi], 0, 0, 0);
    }

    __syncthreads();
  }

#pragma unroll
  for (int mi = 0; mi < 2; ++mi) {
    float inv[4];
#pragma unroll
    for (int r = 0; r < 4; ++r) inv[r] = 1.0f / csum[mi][r];
#pragma unroll
    for (int df = 0; df < 4; ++df)
#pragma unroll
      for (int r = 0; r < 4; ++r) {
        int srow = q0 + mi * 16 + l4 * 4 + r;
        float v = cacc[mi][df][r] * inv[r];
        ctx[((size_t)(b * S_ + srow)) * D_ + h * DEPTH_ + df * 16 + l15] = f2bf(v);
      }
  }
}

extern "C" void kernel_launch(void* const* d_in, const int* in_sizes, int n_in,
                              void* d_out, int out_size, void* d_ws, size_t ws_size,
                              hipStream_t stream) {
  const float* query  = (const float*)d_in[0];
  const float* key_in = (const float*)d_in[1];
  const float* value  = (const float*)d_in[2];
  const float* mask   = (const float*)d_in[3];
  const float* wq = (const float*)d_in[4];
  const float* bq = (const float*)d_in[5];
  const float* wk = (const float*)d_in[6];
  const float* bk = (const float*)d_in[7];
  const float* wv = (const float*)d_in[8];
  const float* bv = (const float*)d_in[9];
  const float* wo = (const float*)d_in[10];
  const float* bo = (const float*)d_in[11];

  char* ws = (char*)d_ws;
  const size_t MB = 1024 * 1024;
  ubf16* WqT = (ubf16*)(ws + 24 * MB);
  ubf16* WkT = (ubf16*)(ws + 26 * MB);
  ubf16* WvT = (ubf16*)(ws + 28 * MB);
  ubf16* WoT = (ubf16*)(ws + 30 * MB);
  ubf16* Qb  = (ubf16*)(ws + 32 * MB);
  ubf16* Kb  = (ubf16*)(ws + 40 * MB);
  ubf16* VTb = (ubf16*)(ws + 48 * MB);
  ubf16* Ctx = (ubf16*)(ws + 56 * MB);

  Tp4 t4;
  t4.W[0] = wq; t4.WT[0] = WqT;
  t4.W[1] = wk; t4.WT[1] = WkT;
  t4.W[2] = wv; t4.WT[2] = WvT;
  t4.W[3] = wo; t4.WT[3] = WoT;
  transpose4_bf16<<<dim3(32, 32, 4), dim3(256), 0, stream>>>(t4);

  GemmArgsF g1;
  g1.u[0] = {query,  WqT, bq, (void*)Qb, 0};
  g1.u[1] = {key_in, WkT, bk, (void*)Kb, 0};
  g1.u[2] = {value,  WvT, bv, (void*)VTb, 1};
  gemm_qkv_fused<<<dim3(8, 32, 3), dim3(512), 0, stream>>>(g1);

  attention_fwd<<<dim3(4, 64), dim3(512), 0, stream>>>(Qb, Kb, VTb, mask, Ctx);

  GemmArgs g2;
  g2.u[0] = {Ctx, WoT, bo, d_out, 2};
  g2.u[1] = g2.u[0];
  g2.u[2] = g2.u[0];
  gemm_bt<<<dim3(8, 32, 1), dim3(512), 0, stream>>>(g2, 4096, 1024);
}